// Round 11
// baseline (248.684 us; speedup 1.0000x reference)
//
#include <hip/hip_runtime.h>
#include <hip/hip_bf16.h>
#include <stdint.h>

typedef unsigned short u16;
typedef __bf16 v8bf __attribute__((ext_vector_type(8)));
typedef float f32x4 __attribute__((ext_vector_type(4)));
typedef float v8f  __attribute__((ext_vector_type(8)));

// ws byte offsets (total 60,817,408 B — proven footprint)
#define WS_WB    0u
#define WS_WIHB  4096u
#define WS_WHHB  397312u
#define WS_W2B   790528u
#define WS_A     921600u
#define WS_GX    2097152u
#define WS_PART  27262976u

// out (fp32) element offsets
#define OUT_STAB   0
#define OUT_EMER   3584
#define OUT_DECAY  7168
#define OUT_CAUSAL 10752
#define OUT_EVO    76288

__device__ __forceinline__ u16 f2bfu(float f){
    union { float f; uint32_t u; } v; v.f = f;
    uint32_t u = v.u;
    return (u16)((u + 0x7fffu + ((u >> 16) & 1u)) >> 16);
}
__device__ __forceinline__ float sigmoidf_fast(float x){
    float e = __builtin_amdgcn_exp2f(-1.4426950408889634f * x);
    return __builtin_amdgcn_rcpf(1.0f + e);
}
__device__ __forceinline__ float tanhf_fast(float x){
    float e = __builtin_amdgcn_exp2f(-2.8853900817779268f * x);
    return __builtin_amdgcn_rcpf(1.0f + e) * 2.0f - 1.0f;
}
__device__ __forceinline__ f32x4 mfma16(v8bf a, v8bf b, f32x4 c){
    return __builtin_amdgcn_mfma_f32_16x16x32_bf16(a, b, c, 0, 0, 0);
}
__device__ __forceinline__ v8bf cvt8(const float* p){
    float4 a = *(const float4*)p;
    float4 b = *(const float4*)(p + 4);
    v8f v = {a.x, a.y, a.z, a.w, b.x, b.y, b.z, b.w};
    return __builtin_convertvector(v, v8bf);
}

// =========== k_pre: Agemm [0,64) | metrics [64,960) | prep-vec8 [960,1185) ==
__global__ __launch_bounds__(256) void k_pre(
        const float* __restrict__ feat, const float* __restrict__ src,
        const float* __restrict__ Wih,  const float* __restrict__ Whh,
        const float* __restrict__ W1,   const float* __restrict__ b1,
        const float* __restrict__ W2,
        u16* __restrict__ wihb, u16* __restrict__ whhb, u16* __restrict__ w2b,
        float* __restrict__ wb, float* __restrict__ A, float* __restrict__ out){
    const int bid = blockIdx.x, tid = threadIdx.x;
    if (bid < 64){
        const int bs0 = bid * 16;
        const int lane = tid & 63, w = tid >> 6;
        const int l15 = lane & 15, quad = lane >> 4;
        v8bf xa[8];
        for (int k = 0; k < 8; k++)
            xa[k] = cvt8(&src[(bs0 + l15) * 256 + k * 32 + quad * 8]);
        f32x4 acc[4];
        for (int nt = 0; nt < 4; nt++) acc[nt] = (f32x4){0.f, 0.f, 0.f, 0.f};
        for (int k = 0; k < 8; k++){
            int d0 = k * 32 + quad * 8;
            for (int nt = 0; nt < 4; nt++){
                int o = w * 64 + nt * 16 + l15;
                v8bf bfr = cvt8(&W1[o * 512 + d0]);
                acc[nt] = mfma16(xa[k], bfr, acc[nt]);
            }
        }
        for (int nt = 0; nt < 4; nt++){
            int o = w * 64 + nt * 16 + l15;
            float bb = b1[o];
            for (int r = 0; r < 4; r++)
                A[(bs0 + quad * 4 + r) * 256 + o] = acc[nt][r] + bb;
        }
    } else if (bid < 960){
        const int pair = (bid - 64) * 4 + (tid >> 6);
        const int l = pair >> 9, s = pair & 511;
        const int lane = tid & 63;
        float stab = 0.f, emer = 0.f;
        for (int b = 0; b < 2; b++){
            const float* p = feat + ((size_t)((b * 8 + l) * 512 + s)) * 256;
            const float* n = feat + ((size_t)((b * 8 + l + 1) * 512 + s)) * 256;
            float4 pv = *(const float4*)(p + lane * 4);
            float4 nv = *(const float4*)(n + lane * 4);
            float dot = pv.x * nv.x + pv.y * nv.y + pv.z * nv.z + pv.w * nv.w;
            float na2 = pv.x * pv.x + pv.y * pv.y + pv.z * pv.z + pv.w * pv.w;
            float nb2 = nv.x * nv.x + nv.y * nv.y + nv.z * nv.z + nv.w * nv.w;
            float ap = ((pv.x > 0.1f) ? 1.f : 0.f) + ((pv.y > 0.1f) ? 1.f : 0.f)
                     + ((pv.z > 0.1f) ? 1.f : 0.f) + ((pv.w > 0.1f) ? 1.f : 0.f);
            float an = ((nv.x > 0.1f) ? 1.f : 0.f) + ((nv.y > 0.1f) ? 1.f : 0.f)
                     + ((nv.z > 0.1f) ? 1.f : 0.f) + ((nv.w > 0.1f) ? 1.f : 0.f);
            for (int off = 32; off > 0; off >>= 1){
                dot += __shfl_xor(dot, off);
                na2 += __shfl_xor(na2, off);
                nb2 += __shfl_xor(nb2, off);
                ap  += __shfl_xor(ap,  off);
                an  += __shfl_xor(an,  off);
            }
            float na = fmaxf(__builtin_sqrtf(na2), 1e-8f);
            float nb = fmaxf(__builtin_sqrtf(nb2), 1e-8f);
            stab += dot / (na * nb);
            emer += (an - ap);
        }
        if (lane == 0){
            int o = l * 512 + s;
            float e = emer * 0.5f * (1.0f / 256.0f);
            out[OUT_STAB  + o] = stab * 0.5f;
            out[OUT_EMER  + o] = e;
            out[OUT_DECAY + o] = -e;
        }
    } else {
        int idx8 = (bid - 960) * 256 + tid;   // < 57600
        if (idx8 < 57344){
            const float* srcp;
            u16* dstp;
            if (idx8 < 24576){ srcp = Wih + idx8 * 8;             dstp = wihb + idx8 * 8; }
            else if (idx8 < 49152){ int i = idx8 - 24576; srcp = Whh + i * 8; dstp = whhb + i * 8; }
            else { int i = idx8 - 49152; srcp = W2 + i * 8; dstp = w2b + i * 8; }
            float4 a = *(const float4*)srcp;
            float4 b = *(const float4*)(srcp + 4);
            union { u16 h[8]; uint4 v; } pk;
            pk.h[0] = f2bfu(a.x); pk.h[1] = f2bfu(a.y);
            pk.h[2] = f2bfu(a.z); pk.h[3] = f2bfu(a.w);
            pk.h[4] = f2bfu(b.x); pk.h[5] = f2bfu(b.y);
            pk.h[6] = f2bfu(b.z); pk.h[7] = f2bfu(b.w);
            *(uint4*)dstp = pk.v;
        } else if (idx8 < 57600){
            int o = idx8 - 57344;
            float s = 0.f;
            const float4* p = (const float4*)&W1[o * 512 + 256];
            for (int j = 0; j < 64; j++){
                float4 v = p[j];
                s += v.x + v.y + v.z + v.w;
            }
            wb[o] = s;
        }
    }
}

// =========== k_mid: interleaved gx (3/7) and causal (4/7) ===================
__global__ __launch_bounds__(256, 2) void k_mid(
        const float* __restrict__ feat, const u16* __restrict__ wihb,
        const float* __restrict__ bih,  float* __restrict__ gxws,
        const float* __restrict__ Aws,  const float* __restrict__ wbws,
        const u16* __restrict__ w2b,    const float* __restrict__ tgt,
        const float* __restrict__ b2,   float* __restrict__ part){
    __shared__ __align__(16) unsigned char smem[71680];
    const int tid = threadIdx.x, lane = tid & 63, w = tid >> 6;
    const int l15 = lane & 15, quad = lane >> 4;
    const int grp = blockIdx.x / 7, q7 = blockIdx.x % 7;   // 896 = 128*7

    if (q7 < 3){
        // ---------------- gx GEMM (id in [0,384)) ----------------
        const int gid = grp * 3 + q7;
        const int mb = gid / 6, nb = gid % 6;
        u16* blds = (u16*)smem;

        {
            int r = tid >> 1, half = tid & 1;
            const uint4* gsrc = (const uint4*)&wihb[(nb * 128 + r) * 256 + half * 128];
            uint4* ldst = (uint4*)&blds[r * 264 + half * 128];
            for (int j = 0; j < 16; j++) ldst[j] = gsrc[j];
        }

        v8bf af[2][8];
        for (int mt = 0; mt < 2; mt++){
            int r = mb * 128 + w * 32 + mt * 16 + l15;
            int n = r >> 3, t = r & 7;
            int b = n >> 9, s = n & 511;
            const float* xp = feat + ((size_t)((b * 8 + t) * 512 + s)) * 256;
            for (int kk = 0; kk < 8; kk++)
                af[mt][kk] = cvt8(xp + kk * 32 + quad * 8);
        }
        __syncthreads();

        f32x4 acc[2][8];
        for (int mt = 0; mt < 2; mt++) for (int nt = 0; nt < 8; nt++)
            acc[mt][nt] = (f32x4){0.f, 0.f, 0.f, 0.f};
        for (int kk = 0; kk < 8; kk++){
            int k0 = kk * 32 + quad * 8;
            for (int nt = 0; nt < 8; nt++){
                v8bf bf = *(const v8bf*)&blds[(nt * 16 + l15) * 264 + k0];
                acc[0][nt] = mfma16(af[0][kk], bf, acc[0][nt]);
                acc[1][nt] = mfma16(af[1][kk], bf, acc[1][nt]);
            }
        }
        for (int nt = 0; nt < 8; nt++){
            int g = nb * 128 + nt * 16 + l15;
            float bias = bih[g];
            for (int mt = 0; mt < 2; mt++)
                for (int rr = 0; rr < 4; rr++){
                    int row = mb * 128 + w * 32 + mt * 16 + quad * 4 + rr;
                    gxws[(size_t)row * 768 + g] = acc[mt][nt][rr] + bias;
                }
        }
        return;
    }

    // ---------------- causal (id in [0,512)) ----------------
    const int bidc = grp * 4 + (q7 - 3);
    const int chunk = bidc >> 2, q = bidc & 3;
    const int i0 = (q & 1) * 128, p0 = (q >> 1) * 128;

    u16*  w2s  = (u16*)smem;               // 67584 B
    float* a_db = (float*)(smem + 67584);  //  2048 B  [2][256]
    float* t_db = (float*)(smem + 69632);  //  1024 B  [2][128]
    float* wb_s = (float*)(smem + 70656);  //  1024 B

    {
        int r = tid >> 1, half = tid & 1;
        const uint4* gsrc = (const uint4*)&w2b[(p0 + r) * 256 + half * 128];
        uint4* ldst = (uint4*)&w2s[r * 264 + half * 128];
        for (int j = 0; j < 16; j++) ldst[j] = gsrc[j];
    }
    wb_s[tid] = wbws[tid];
    a_db[tid] = Aws[chunk * 8 * 256 + tid];
    if (tid < 128) t_db[tid] = tgt[(chunk * 8) * 256 + i0 + tid];

    float bb[8];
    for (int nt = 0; nt < 8; nt++) bb[nt] = b2[p0 + nt * 16 + l15];

    f32x4 sig[2][8];
    for (int mt = 0; mt < 2; mt++) for (int nt = 0; nt < 8; nt++)
        sig[mt][nt] = (f32x4){0.f, 0.f, 0.f, 0.f};

    const v8f z8 = {0.f, 0.f, 0.f, 0.f, 0.f, 0.f, 0.f, 0.f};

    for (int ss = 0; ss < 8; ss++){
        __syncthreads();
        if (ss < 7){
            int nb = (ss + 1) & 1;
            a_db[nb * 256 + tid] = Aws[(chunk * 8 + ss + 1) * 256 + tid];
            if (tid < 128) t_db[nb * 128 + tid] = tgt[(chunk * 8 + ss + 1) * 256 + i0 + tid];
        }
        const int cb = ss & 1;
        float tv0 = t_db[cb * 128 + w * 32 + l15];
        float tv1 = t_db[cb * 128 + w * 32 + 16 + l15];

        f32x4 acc[2][8];
        for (int mt = 0; mt < 2; mt++) for (int nt = 0; nt < 8; nt++)
            acc[mt][nt] = (f32x4){0.f, 0.f, 0.f, 0.f};

        for (int k = 0; k < 8; k++){
            const int o0 = k * 32 + quad * 8;
            float4 a0  = *(const float4*)&a_db[cb * 256 + o0];
            float4 a1  = *(const float4*)&a_db[cb * 256 + o0 + 4];
            float4 w0  = *(const float4*)&wb_s[o0];
            float4 w1v = *(const float4*)&wb_s[o0 + 4];
            v8f a8 = {a0.x, a0.y, a0.z, a0.w, a1.x, a1.y, a1.z, a1.w};
            v8f w8 = {w0.x, w0.y, w0.z, w0.w, w1v.x, w1v.y, w1v.z, w1v.w};
            v8f h0v = __builtin_elementwise_max(a8 + tv0 * w8, z8);
            v8f h1v = __builtin_elementwise_max(a8 + tv1 * w8, z8);
            v8bf afr0 = __builtin_convertvector(h0v, v8bf);
            v8bf afr1 = __builtin_convertvector(h1v, v8bf);
            for (int nt = 0; nt < 8; nt++){
                v8bf bfr = *(const v8bf*)&w2s[(nt * 16 + l15) * 264 + o0];
                acc[0][nt] = mfma16(afr0, bfr, acc[0][nt]);
                acc[1][nt] = mfma16(afr1, bfr, acc[1][nt]);
            }
        }
        for (int mt = 0; mt < 2; mt++)
            for (int nt = 0; nt < 8; nt++)
                for (int r = 0; r < 4; r++)
                    sig[mt][nt][r] += sigmoidf_fast(acc[mt][nt][r] + bb[nt]);
    }

    float* pp = part + (size_t)chunk * 65536;
    for (int mt = 0; mt < 2; mt++)
        for (int r = 0; r < 4; r++){
            int i = i0 + w * 32 + mt * 16 + quad * 4 + r;
            for (int nt = 0; nt < 8; nt++){
                int p = p0 + nt * 16 + l15;
                pp[i * 256 + p] = sig[mt][nt][r];
            }
        }
}

// =========== k_final: gruseq (in-register gates) [0,64) | creduce [64,192) ==
__global__ __launch_bounds__(512) void k_final(
        const float* __restrict__ gxws, const u16* __restrict__ whhb,
        const float* __restrict__ bhh, const float* __restrict__ part,
        float* __restrict__ out){
    if (blockIdx.x >= 64){
        const int idx = (blockIdx.x - 64) * 512 + threadIdx.x;  // 65536
        float s = 0.f;
        for (int c = 0; c < 128; c++)
            s += part[(size_t)c * 65536 + idx];
        out[OUT_CAUSAL + idx] = s * (1.0f / 1024.0f);
        return;
    }
    // ---- sequential GRU: wave wv owns d-slice [wv*32, wv*32+32) x {r,z,n} ----
    const int n0 = blockIdx.x * 16;
    const int tid = threadIdx.x, lane = tid & 63, wv = tid >> 6;
    const int l15 = lane & 15, quad = lane >> 4;
    const int D0 = wv * 32;

    __shared__ float h_lds[2][16 * 260];

    // gate tiles: 0:r@D0  1:r@D0+16  2:z@D0  3:z@D0+16  4:n@D0  5:n@D0+16
    const int gt[6] = {D0, D0 + 16, 256 + D0, 256 + D0 + 16, 512 + D0, 512 + D0 + 16};

    v8bf wreg[3][8];   // preload tiles 0,1,2
    for (int j = 0; j < 3; j++)
        for (int k = 0; k < 8; k++)
            wreg[j][k] = *(const v8bf*)&whhb[(gt[j] + l15) * 256 + k * 32 + quad * 8];

    float bias[6];
    for (int j = 0; j < 6; j++) bias[j] = bhh[gt[j] + l15];

    for (int e = tid; e < 16 * 260; e += 512) h_lds[0][e] = 0.f;
    __syncthreads();

    for (int t = 0; t < 8; t++){
        const int cur = t & 1, nxt = cur ^ 1;
        // gx prefetch: per lane, 6 tiles x 4 seqs (coalesced per 16 lanes)
        float gxv[6][4];
        for (int rr = 0; rr < 4; rr++){
            const float* gp = gxws + ((size_t)(n0 + quad * 4 + rr) * 8 + t) * 768;
            for (int j = 0; j < 6; j++)
                gxv[j][rr] = gp[gt[j] + l15];
        }
        // ha from current h buffer
        v8bf ha[8];
        for (int k = 0; k < 8; k++)
            ha[k] = cvt8(&h_lds[cur][l15 * 260 + k * 32 + quad * 8]);
        f32x4 acc[6];
        for (int j = 0; j < 6; j++) acc[j] = (f32x4){0.f, 0.f, 0.f, 0.f};
        for (int k = 0; k < 8; k++){
            int dk = k * 32 + quad * 8;
            acc[0] = mfma16(ha[k], wreg[0][k], acc[0]);
            acc[1] = mfma16(ha[k], wreg[1][k], acc[1]);
            acc[2] = mfma16(ha[k], wreg[2][k], acc[2]);
            for (int j = 3; j < 6; j++){
                v8bf bf = *(const v8bf*)&whhb[(gt[j] + l15) * 256 + dk];
                acc[j] = mfma16(ha[k], bf, acc[j]);
            }
        }
        // in-register pointwise: lane has r,z,n for (4 seqs x 2 cols)
        for (int c = 0; c < 2; c++){
            const int d = D0 + c * 16 + l15;
            for (int rr = 0; rr < 4; rr++){
                const int seq = quad * 4 + rr;
                float r  = sigmoidf_fast(gxv[c][rr]     + acc[c][rr]     + bias[c]);
                float z  = sigmoidf_fast(gxv[2 + c][rr] + acc[2 + c][rr] + bias[2 + c]);
                float nn = tanhf_fast(fmaf(r, acc[4 + c][rr] + bias[4 + c], gxv[4 + c][rr]));
                float hold = h_lds[cur][seq * 260 + d];
                float hnew = (1.f - z) * nn + z * hold;
                h_lds[nxt][seq * 260 + d] = hnew;
                out[OUT_EVO + ((size_t)(n0 + seq) * 8 + t) * 256 + d] = hnew;
            }
        }
        __syncthreads();
    }
}

extern "C" void kernel_launch(void* const* d_in, const int* in_sizes, int n_in,
                              void* d_out, int out_size, void* d_ws, size_t ws_size,
                              hipStream_t stream){
    const float* feat = (const float*)d_in[0];
    const float* src  = (const float*)d_in[1];
    const float* tgt  = (const float*)d_in[2];
    const float* Wih  = (const float*)d_in[3];
    const float* Whh  = (const float*)d_in[4];
    const float* bih  = (const float*)d_in[5];
    const float* bhh  = (const float*)d_in[6];
    const float* W1   = (const float*)d_in[7];
    const float* b1   = (const float*)d_in[8];
    const float* W2   = (const float*)d_in[9];
    const float* b2   = (const float*)d_in[10];
    float* out = (float*)d_out;
    char* ws = (char*)d_ws;

    float* wb   = (float*)(ws + WS_WB);
    u16*   wihb = (u16*)(ws + WS_WIHB);
    u16*   whhb = (u16*)(ws + WS_WHHB);
    u16*   w2b  = (u16*)(ws + WS_W2B);
    float* Aws  = (float*)(ws + WS_A);
    float* gxws = (float*)(ws + WS_GX);
    float* part = (float*)(ws + WS_PART);

    k_pre  <<<1185, 256, 0, stream>>>(feat, src, Wih, Whh, W1, b1, W2,
                                      wihb, whhb, w2b, wb, Aws, out);
    k_mid  <<<896,  256, 0, stream>>>(feat, wihb, bih, gxws,
                                      Aws, wb, w2b, tgt, b2, part);
    k_final<<<192,  512, 0, stream>>>(gxws, whhb, bhh, part, out);
}

// Round 12
// 219.927 us; speedup vs baseline: 1.1308x; 1.1308x over previous
//
#include <hip/hip_runtime.h>
#include <hip/hip_bf16.h>
#include <stdint.h>

typedef unsigned short u16;
typedef __bf16 v8bf __attribute__((ext_vector_type(8)));
typedef float f32x4 __attribute__((ext_vector_type(4)));

// ws byte offsets (total 60,817,408 B — proven footprint)
#define WS_WB    0u
#define WS_WIHB  4096u
#define WS_WHHB  397312u
#define WS_W2B   790528u
#define WS_A     921600u
#define WS_GX    2097152u
#define WS_PART  27262976u

// out (fp32) element offsets
#define OUT_STAB   0
#define OUT_EMER   3584
#define OUT_DECAY  7168
#define OUT_CAUSAL 10752
#define OUT_EVO    76288

__device__ __forceinline__ u16 f2bfu(float f){
    union { float f; uint32_t u; } v; v.f = f;
    uint32_t u = v.u;
    return (u16)((u + 0x7fffu + ((u >> 16) & 1u)) >> 16);
}
__device__ __forceinline__ float sigmoidf_fast(float x){
    float e = __builtin_amdgcn_exp2f(-1.4426950408889634f * x);
    return __builtin_amdgcn_rcpf(1.0f + e);
}
__device__ __forceinline__ float tanhf_fast(float x){
    float e = __builtin_amdgcn_exp2f(-2.8853900817779268f * x);
    return __builtin_amdgcn_rcpf(1.0f + e) * 2.0f - 1.0f;
}
__device__ __forceinline__ f32x4 mfma16(v8bf a, v8bf b, f32x4 c){
    return __builtin_amdgcn_mfma_f32_16x16x32_bf16(a, b, c, 0, 0, 0);
}
__device__ __forceinline__ v8bf cvt8(const float* p){
    float4 a = *(const float4*)p;
    float4 b = *(const float4*)(p + 4);
    v8bf r;
    r[0] = (__bf16)a.x; r[1] = (__bf16)a.y; r[2] = (__bf16)a.z; r[3] = (__bf16)a.w;
    r[4] = (__bf16)b.x; r[5] = (__bf16)b.y; r[6] = (__bf16)b.z; r[7] = (__bf16)b.w;
    return r;
}

// =========== k_pre: Agemm [0,64) | metrics [64,960) | prep-vec8 [960,1185) ==
__global__ __launch_bounds__(256) void k_pre(
        const float* __restrict__ feat, const float* __restrict__ src,
        const float* __restrict__ Wih,  const float* __restrict__ Whh,
        const float* __restrict__ W1,   const float* __restrict__ b1,
        const float* __restrict__ W2,
        u16* __restrict__ wihb, u16* __restrict__ whhb, u16* __restrict__ w2b,
        float* __restrict__ wb, float* __restrict__ A, float* __restrict__ out){
    const int bid = blockIdx.x, tid = threadIdx.x;
    if (bid < 64){
        const int bs0 = bid * 16;
        const int lane = tid & 63, w = tid >> 6;
        const int l15 = lane & 15, quad = lane >> 4;
        v8bf xa[8];
        for (int k = 0; k < 8; k++)
            xa[k] = cvt8(&src[(bs0 + l15) * 256 + k * 32 + quad * 8]);
        f32x4 acc[4];
        for (int nt = 0; nt < 4; nt++) acc[nt] = (f32x4){0.f, 0.f, 0.f, 0.f};
        for (int k = 0; k < 8; k++){
            int d0 = k * 32 + quad * 8;
            for (int nt = 0; nt < 4; nt++){
                int o = w * 64 + nt * 16 + l15;
                v8bf bfr = cvt8(&W1[o * 512 + d0]);
                acc[nt] = mfma16(xa[k], bfr, acc[nt]);
            }
        }
        for (int nt = 0; nt < 4; nt++){
            int o = w * 64 + nt * 16 + l15;
            float bb = b1[o];
            for (int r = 0; r < 4; r++)
                A[(bs0 + quad * 4 + r) * 256 + o] = acc[nt][r] + bb;
        }
    } else if (bid < 960){
        const int pair = (bid - 64) * 4 + (tid >> 6);
        const int l = pair >> 9, s = pair & 511;
        const int lane = tid & 63;
        float stab = 0.f, emer = 0.f;
        for (int b = 0; b < 2; b++){
            const float* p = feat + ((size_t)((b * 8 + l) * 512 + s)) * 256;
            const float* n = feat + ((size_t)((b * 8 + l + 1) * 512 + s)) * 256;
            float4 pv = *(const float4*)(p + lane * 4);
            float4 nv = *(const float4*)(n + lane * 4);
            float dot = pv.x * nv.x + pv.y * nv.y + pv.z * nv.z + pv.w * nv.w;
            float na2 = pv.x * pv.x + pv.y * pv.y + pv.z * pv.z + pv.w * pv.w;
            float nb2 = nv.x * nv.x + nv.y * nv.y + nv.z * nv.z + nv.w * nv.w;
            float ap = ((pv.x > 0.1f) ? 1.f : 0.f) + ((pv.y > 0.1f) ? 1.f : 0.f)
                     + ((pv.z > 0.1f) ? 1.f : 0.f) + ((pv.w > 0.1f) ? 1.f : 0.f);
            float an = ((nv.x > 0.1f) ? 1.f : 0.f) + ((nv.y > 0.1f) ? 1.f : 0.f)
                     + ((nv.z > 0.1f) ? 1.f : 0.f) + ((nv.w > 0.1f) ? 1.f : 0.f);
            for (int off = 32; off > 0; off >>= 1){
                dot += __shfl_xor(dot, off);
                na2 += __shfl_xor(na2, off);
                nb2 += __shfl_xor(nb2, off);
                ap  += __shfl_xor(ap,  off);
                an  += __shfl_xor(an,  off);
            }
            float na = fmaxf(__builtin_sqrtf(na2), 1e-8f);
            float nb = fmaxf(__builtin_sqrtf(nb2), 1e-8f);
            stab += dot / (na * nb);
            emer += (an - ap);
        }
        if (lane == 0){
            int o = l * 512 + s;
            float e = emer * 0.5f * (1.0f / 256.0f);
            out[OUT_STAB  + o] = stab * 0.5f;
            out[OUT_EMER  + o] = e;
            out[OUT_DECAY + o] = -e;
        }
    } else {
        int idx8 = (bid - 960) * 256 + tid;   // < 57600
        if (idx8 < 57344){
            const float* srcp;
            u16* dstp;
            if (idx8 < 24576){ srcp = Wih + idx8 * 8;             dstp = wihb + idx8 * 8; }
            else if (idx8 < 49152){ int i = idx8 - 24576; srcp = Whh + i * 8; dstp = whhb + i * 8; }
            else { int i = idx8 - 49152; srcp = W2 + i * 8; dstp = w2b + i * 8; }
            float4 a = *(const float4*)srcp;
            float4 b = *(const float4*)(srcp + 4);
            union { u16 h[8]; uint4 v; } pk;
            pk.h[0] = f2bfu(a.x); pk.h[1] = f2bfu(a.y);
            pk.h[2] = f2bfu(a.z); pk.h[3] = f2bfu(a.w);
            pk.h[4] = f2bfu(b.x); pk.h[5] = f2bfu(b.y);
            pk.h[6] = f2bfu(b.z); pk.h[7] = f2bfu(b.w);
            *(uint4*)dstp = pk.v;
        } else if (idx8 < 57600){
            int o = idx8 - 57344;
            float s = 0.f;
            const float4* p = (const float4*)&W1[o * 512 + 256];
            for (int j = 0; j < 64; j++){
                float4 v = p[j];
                s += v.x + v.y + v.z + v.w;
            }
            wb[o] = s;
        }
    }
}

// =========== k_mid: gx [0,384) | causal [384,896) — XOR-swizzled LDS ========
// LDS tile layout: row pl (128 rows x 32 chunks of 16B); chunk c stored at
// slot (c ^ (pl & 31)) -> 16 l15-lanes hit 16 distinct slots = conflict-free.
__global__ __launch_bounds__(256, 2) void k_mid(
        const float* __restrict__ feat, const u16* __restrict__ wihb,
        const float* __restrict__ bih,  float* __restrict__ gxws,
        const float* __restrict__ Aws,  const float* __restrict__ wbws,
        const u16* __restrict__ w2b,    const float* __restrict__ tgt,
        const float* __restrict__ b2,   float* __restrict__ part){
    __shared__ __align__(16) unsigned char smem[69632];
    const int tid = threadIdx.x, lane = tid & 63, w = tid >> 6;
    const int l15 = lane & 15, quad = lane >> 4;

    if (blockIdx.x < 384){
        // ---------------- gx GEMM ----------------
        const int mb = blockIdx.x / 6, nb = blockIdx.x % 6;
        u16* blds = (u16*)smem;   // 128 x 256 u16, swizzled

        {
            int r = tid >> 1, half = tid & 1;
            const uint4* gsrc = (const uint4*)&wihb[(nb * 128 + r) * 256 + half * 128];
            for (int j = 0; j < 16; j++){
                int c = half * 16 + j;
                *(uint4*)&blds[r * 256 + ((c ^ (r & 31)) << 3)] = gsrc[j];
            }
        }

        v8bf af[2][8];
        for (int mt = 0; mt < 2; mt++){
            int r = mb * 128 + w * 32 + mt * 16 + l15;
            int n = r >> 3, t = r & 7;
            int b = n >> 9, s = n & 511;
            const float* xp = feat + ((size_t)((b * 8 + t) * 512 + s)) * 256;
            for (int kk = 0; kk < 8; kk++)
                af[mt][kk] = cvt8(xp + kk * 32 + quad * 8);
        }
        __syncthreads();

        f32x4 acc[2][8];
        for (int mt = 0; mt < 2; mt++) for (int nt = 0; nt < 8; nt++)
            acc[mt][nt] = (f32x4){0.f, 0.f, 0.f, 0.f};
        for (int kk = 0; kk < 8; kk++){
            int kq = kk * 4 + quad;
            for (int nt = 0; nt < 8; nt++){
                int pl = nt * 16 + l15;
                v8bf bf = *(const v8bf*)&blds[pl * 256 + ((kq ^ (pl & 31)) << 3)];
                acc[0][nt] = mfma16(af[0][kk], bf, acc[0][nt]);
                acc[1][nt] = mfma16(af[1][kk], bf, acc[1][nt]);
            }
        }
        for (int nt = 0; nt < 8; nt++){
            int g = nb * 128 + nt * 16 + l15;
            float bias = bih[g];
            for (int mt = 0; mt < 2; mt++)
                for (int rr = 0; rr < 4; rr++){
                    int row = mb * 128 + w * 32 + mt * 16 + quad * 4 + rr;
                    gxws[(size_t)row * 768 + g] = acc[mt][nt][rr] + bias;
                }
        }
        return;
    }

    // ---------------- causal ----------------
    const int bidc = blockIdx.x - 384;
    const int chunk = bidc >> 2, q = bidc & 3;
    const int i0 = (q & 1) * 128, p0 = (q >> 1) * 128;

    u16*  w2s  = (u16*)smem;               // 65536 B, swizzled
    float* a_db = (float*)(smem + 65536);  //  2048 B  [2][256]
    float* t_db = (float*)(smem + 67584);  //  1024 B  [2][128]
    float* wb_s = (float*)(smem + 68608);  //  1024 B

    {
        int r = tid >> 1, half = tid & 1;
        const uint4* gsrc = (const uint4*)&w2b[(p0 + r) * 256 + half * 128];
        for (int j = 0; j < 16; j++){
            int c = half * 16 + j;
            *(uint4*)&w2s[r * 256 + ((c ^ (r & 31)) << 3)] = gsrc[j];
        }
    }
    wb_s[tid] = wbws[tid];
    a_db[tid] = Aws[chunk * 8 * 256 + tid];
    if (tid < 128) t_db[tid] = tgt[(chunk * 8) * 256 + i0 + tid];

    float bb[8];
    for (int nt = 0; nt < 8; nt++) bb[nt] = b2[p0 + nt * 16 + l15];

    f32x4 sig[2][8];
    for (int mt = 0; mt < 2; mt++) for (int nt = 0; nt < 8; nt++)
        sig[mt][nt] = (f32x4){0.f, 0.f, 0.f, 0.f};

    for (int ss = 0; ss < 8; ss++){
        __syncthreads();
        if (ss < 7){
            int nb = (ss + 1) & 1;
            a_db[nb * 256 + tid] = Aws[(chunk * 8 + ss + 1) * 256 + tid];
            if (tid < 128) t_db[nb * 128 + tid] = tgt[(chunk * 8 + ss + 1) * 256 + i0 + tid];
        }
        const int cb = ss & 1;
        float tv0 = t_db[cb * 128 + w * 32 + l15];
        float tv1 = t_db[cb * 128 + w * 32 + 16 + l15];

        f32x4 acc[2][8];
        for (int mt = 0; mt < 2; mt++) for (int nt = 0; nt < 8; nt++)
            acc[mt][nt] = (f32x4){0.f, 0.f, 0.f, 0.f};

        for (int k = 0; k < 8; k++){
            const int o0 = k * 32 + quad * 8;
            const int kq = k * 4 + quad;
            float4 a0  = *(const float4*)&a_db[cb * 256 + o0];
            float4 a1  = *(const float4*)&a_db[cb * 256 + o0 + 4];
            float4 w0  = *(const float4*)&wb_s[o0];
            float4 w1v = *(const float4*)&wb_s[o0 + 4];
            v8bf afr0, afr1;
            {
                float t = tv0;
                afr0[0] = (__bf16)fmaxf(fmaf(t, w0.x,  a0.x), 0.f);
                afr0[1] = (__bf16)fmaxf(fmaf(t, w0.y,  a0.y), 0.f);
                afr0[2] = (__bf16)fmaxf(fmaf(t, w0.z,  a0.z), 0.f);
                afr0[3] = (__bf16)fmaxf(fmaf(t, w0.w,  a0.w), 0.f);
                afr0[4] = (__bf16)fmaxf(fmaf(t, w1v.x, a1.x), 0.f);
                afr0[5] = (__bf16)fmaxf(fmaf(t, w1v.y, a1.y), 0.f);
                afr0[6] = (__bf16)fmaxf(fmaf(t, w1v.z, a1.z), 0.f);
                afr0[7] = (__bf16)fmaxf(fmaf(t, w1v.w, a1.w), 0.f);
            }
            {
                float t = tv1;
                afr1[0] = (__bf16)fmaxf(fmaf(t, w0.x,  a0.x), 0.f);
                afr1[1] = (__bf16)fmaxf(fmaf(t, w0.y,  a0.y), 0.f);
                afr1[2] = (__bf16)fmaxf(fmaf(t, w0.z,  a0.z), 0.f);
                afr1[3] = (__bf16)fmaxf(fmaf(t, w0.w,  a0.w), 0.f);
                afr1[4] = (__bf16)fmaxf(fmaf(t, w1v.x, a1.x), 0.f);
                afr1[5] = (__bf16)fmaxf(fmaf(t, w1v.y, a1.y), 0.f);
                afr1[6] = (__bf16)fmaxf(fmaf(t, w1v.z, a1.z), 0.f);
                afr1[7] = (__bf16)fmaxf(fmaf(t, w1v.w, a1.w), 0.f);
            }
            for (int nt = 0; nt < 8; nt++){
                int pl = nt * 16 + l15;
                v8bf bfr = *(const v8bf*)&w2s[pl * 256 + ((kq ^ (pl & 31)) << 3)];
                acc[0][nt] = mfma16(afr0, bfr, acc[0][nt]);
                acc[1][nt] = mfma16(afr1, bfr, acc[1][nt]);
            }
        }
        for (int mt = 0; mt < 2; mt++)
            for (int nt = 0; nt < 8; nt++)
                for (int r = 0; r < 4; r++)
                    sig[mt][nt][r] += sigmoidf_fast(acc[mt][nt][r] + bb[nt]);
    }

    float* pp = part + (size_t)chunk * 65536;
    for (int mt = 0; mt < 2; mt++)
        for (int r = 0; r < 4; r++){
            int i = i0 + w * 32 + mt * 16 + quad * 4 + r;
            for (int nt = 0; nt < 8; nt++){
                int p = p0 + nt * 16 + l15;
                pp[i * 256 + p] = sig[mt][nt][r];
            }
        }
}

// =========== k_final: gruseq [0,64) | creduce [64,192)  (r10-proven) ========
__global__ __launch_bounds__(512) void k_final(
        const float* __restrict__ gxws, const u16* __restrict__ whhb,
        const float* __restrict__ bhh, const float* __restrict__ part,
        float* __restrict__ out){
    if (blockIdx.x >= 64){
        const int idx = (blockIdx.x - 64) * 512 + threadIdx.x;  // 65536
        float s = 0.f;
        for (int c = 0; c < 128; c++)
            s += part[(size_t)c * 65536 + idx];
        out[OUT_CAUSAL + idx] = s * (1.0f / 1024.0f);
        return;
    }
    const int n0 = blockIdx.x * 16;
    const int tid = threadIdx.x, lane = tid & 63, wv = tid >> 6;
    const int l15 = lane & 15, quad = lane >> 4;
    const int g0 = wv * 96;

    __shared__ float h_lds[16 * 260];
    __shared__ float g_lds[16 * 776];

    v8bf wreg[3][8];
    for (int nt = 0; nt < 3; nt++)
        for (int k = 0; k < 8; k++)
            wreg[nt][k] = *(const v8bf*)&whhb[(g0 + nt * 16 + l15) * 256 + k * 32 + quad * 8];

    float bias[6];
    for (int nt = 0; nt < 6; nt++) bias[nt] = bhh[g0 + nt * 16 + l15];

    for (int e = tid; e < 16 * 260; e += 512) h_lds[e] = 0.f;

    const int seq = tid >> 5, d0 = (tid & 31) * 8;
    const float* gxbase = gxws + (size_t)(n0 + seq) * 8 * 768 + d0;
    float* evobase = out + OUT_EVO + (size_t)(n0 + seq) * 8 * 256 + d0;
    __syncthreads();

    for (int t = 0; t < 8; t++){
        v8bf ha[8];
        for (int k = 0; k < 8; k++)
            ha[k] = cvt8(&h_lds[l15 * 260 + k * 32 + quad * 8]);
        f32x4 acc[6];
        for (int nt = 0; nt < 6; nt++) acc[nt] = (f32x4){0.f, 0.f, 0.f, 0.f};
        for (int k = 0; k < 8; k++){
            int dk = k * 32 + quad * 8;
            acc[0] = mfma16(ha[k], wreg[0][k], acc[0]);
            acc[1] = mfma16(ha[k], wreg[1][k], acc[1]);
            acc[2] = mfma16(ha[k], wreg[2][k], acc[2]);
            for (int nt = 3; nt < 6; nt++){
                v8bf bf = *(const v8bf*)&whhb[(g0 + nt * 16 + l15) * 256 + dk];
                acc[nt] = mfma16(ha[k], bf, acc[nt]);
            }
        }
        for (int nt = 0; nt < 6; nt++){
            int g = g0 + nt * 16 + l15;
            for (int rr = 0; rr < 4; rr++)
                g_lds[(quad * 4 + rr) * 776 + g] = acc[nt][rr] + bias[nt];
        }
        const float* gxp = gxbase + (size_t)t * 768;
        float4 x0a = *(const float4*)(gxp);
        float4 x0b = *(const float4*)(gxp + 4);
        float4 x1a = *(const float4*)(gxp + 256);
        float4 x1b = *(const float4*)(gxp + 260);
        float4 x2a = *(const float4*)(gxp + 512);
        float4 x2b = *(const float4*)(gxp + 516);
        __syncthreads();
        {
            const float* gh = &g_lds[seq * 776];
            float* hp = &h_lds[seq * 260 + d0];
            float4 g0a = *(const float4*)&gh[d0];
            float4 g0b = *(const float4*)&gh[d0 + 4];
            float4 g1a = *(const float4*)&gh[256 + d0];
            float4 g1b = *(const float4*)&gh[260 + d0];
            float4 g2a = *(const float4*)&gh[512 + d0];
            float4 g2b = *(const float4*)&gh[516 + d0];
            float4 h0 = *(const float4*)hp;
            float4 h1 = *(const float4*)(hp + 4);
            float gxr[8] = {x0a.x, x0a.y, x0a.z, x0a.w, x0b.x, x0b.y, x0b.z, x0b.w};
            float gxz[8] = {x1a.x, x1a.y, x1a.z, x1a.w, x1b.x, x1b.y, x1b.z, x1b.w};
            float gxn[8] = {x2a.x, x2a.y, x2a.z, x2a.w, x2b.x, x2b.y, x2b.z, x2b.w};
            float ghr[8] = {g0a.x, g0a.y, g0a.z, g0a.w, g0b.x, g0b.y, g0b.z, g0b.w};
            float ghz[8] = {g1a.x, g1a.y, g1a.z, g1a.w, g1b.x, g1b.y, g1b.z, g1b.w};
            float ghn[8] = {g2a.x, g2a.y, g2a.z, g2a.w, g2b.x, g2b.y, g2b.z, g2b.w};
            float hold[8] = {h0.x, h0.y, h0.z, h0.w, h1.x, h1.y, h1.z, h1.w};
            float hn[8];
            #pragma unroll
            for (int j = 0; j < 8; j++){
                float r  = sigmoidf_fast(gxr[j] + ghr[j]);
                float z  = sigmoidf_fast(gxz[j] + ghz[j]);
                float nn = tanhf_fast(fmaf(r, ghn[j], gxn[j]));
                hn[j] = (1.f - z) * nn + z * hold[j];
            }
            float4 v0 = {hn[0], hn[1], hn[2], hn[3]};
            float4 v1 = {hn[4], hn[5], hn[6], hn[7]};
            *(float4*)hp       = v0;
            *(float4*)(hp + 4) = v1;
            float* ep = evobase + (size_t)t * 256;
            *(float4*)ep       = v0;
            *(float4*)(ep + 4) = v1;
        }
        __syncthreads();
    }
}

extern "C" void kernel_launch(void* const* d_in, const int* in_sizes, int n_in,
                              void* d_out, int out_size, void* d_ws, size_t ws_size,
                              hipStream_t stream){
    const float* feat = (const float*)d_in[0];
    const float* src  = (const float*)d_in[1];
    const float* tgt  = (const float*)d_in[2];
    const float* Wih  = (const float*)d_in[3];
    const float* Whh  = (const float*)d_in[4];
    const float* bih  = (const float*)d_in[5];
    const float* bhh  = (const float*)d_in[6];
    const float* W1   = (const float*)d_in[7];
    const float* b1   = (const float*)d_in[8];
    const float* W2   = (const float*)d_in[9];
    const float* b2   = (const float*)d_in[10];
    float* out = (float*)d_out;
    char* ws = (char*)d_ws;

    float* wb   = (float*)(ws + WS_WB);
    u16*   wihb = (u16*)(ws + WS_WIHB);
    u16*   whhb = (u16*)(ws + WS_WHHB);
    u16*   w2b  = (u16*)(ws + WS_W2B);
    float* Aws  = (float*)(ws + WS_A);
    float* gxws = (float*)(ws + WS_GX);
    float* part = (float*)(ws + WS_PART);

    k_pre  <<<1185, 256, 0, stream>>>(feat, src, Wih, Whh, W1, b1, W2,
                                      wihb, whhb, w2b, wb, Aws, out);
    k_mid  <<<896,  256, 0, stream>>>(feat, wihb, bih, gxws,
                                      Aws, wb, w2b, tgt, b2, part);
    k_final<<<192,  512, 0, stream>>>(gxws, whhb, bhh, part, out);
}

// Round 13
// 214.196 us; speedup vs baseline: 1.1610x; 1.0268x over previous
//
#include <hip/hip_runtime.h>
#include <hip/hip_bf16.h>
#include <stdint.h>

typedef unsigned short u16;
typedef __bf16 v8bf __attribute__((ext_vector_type(8)));
typedef float f32x4 __attribute__((ext_vector_type(4)));

// ws byte offsets (total 60,817,408 B — proven footprint)
#define WS_WB    0u
#define WS_WIHB  4096u
#define WS_WHHB  397312u
#define WS_W2B   790528u
#define WS_A     921600u
#define WS_GX    2097152u     // u16[8192*768] = 12.6 MB (bf16 now)
#define WS_PART  27262976u

// out (fp32) element offsets
#define OUT_STAB   0
#define OUT_EMER   3584
#define OUT_DECAY  7168
#define OUT_CAUSAL 10752
#define OUT_EVO    76288

__device__ __forceinline__ u16 f2bfu(float f){
    union { float f; uint32_t u; } v; v.f = f;
    uint32_t u = v.u;
    return (u16)((u + 0x7fffu + ((u >> 16) & 1u)) >> 16);
}
__device__ __forceinline__ float hi2f(uint32_t w){
    union { uint32_t u; float f; } v; v.u = w & 0xFFFF0000u; return v.f;
}
__device__ __forceinline__ float lo2f(uint32_t w){
    union { uint32_t u; float f; } v; v.u = w << 16; return v.f;
}
__device__ __forceinline__ float sigmoidf_fast(float x){
    float e = __builtin_amdgcn_exp2f(-1.4426950408889634f * x);
    return __builtin_amdgcn_rcpf(1.0f + e);
}
__device__ __forceinline__ float tanhf_fast(float x){
    float e = __builtin_amdgcn_exp2f(-2.8853900817779268f * x);
    return __builtin_amdgcn_rcpf(1.0f + e) * 2.0f - 1.0f;
}
__device__ __forceinline__ f32x4 mfma16(v8bf a, v8bf b, f32x4 c){
    return __builtin_amdgcn_mfma_f32_16x16x32_bf16(a, b, c, 0, 0, 0);
}
__device__ __forceinline__ v8bf cvt8(const float* p){
    float4 a = *(const float4*)p;
    float4 b = *(const float4*)(p + 4);
    v8bf r;
    r[0] = (__bf16)a.x; r[1] = (__bf16)a.y; r[2] = (__bf16)a.z; r[3] = (__bf16)a.w;
    r[4] = (__bf16)b.x; r[5] = (__bf16)b.y; r[6] = (__bf16)b.z; r[7] = (__bf16)b.w;
    return r;
}

// =========== k_pre: Agemm [0,64) | prep-vec8 [64,289) =======================
__global__ __launch_bounds__(256) void k_pre(
        const float* __restrict__ src,
        const float* __restrict__ Wih,  const float* __restrict__ Whh,
        const float* __restrict__ W1,   const float* __restrict__ b1,
        const float* __restrict__ W2,
        u16* __restrict__ wihb, u16* __restrict__ whhb, u16* __restrict__ w2b,
        float* __restrict__ wb, float* __restrict__ A){
    const int bid = blockIdx.x, tid = threadIdx.x;
    if (bid < 64){
        const int bs0 = bid * 16;
        const int lane = tid & 63, w = tid >> 6;
        const int l15 = lane & 15, quad = lane >> 4;
        v8bf xa[8];
        for (int k = 0; k < 8; k++)
            xa[k] = cvt8(&src[(bs0 + l15) * 256 + k * 32 + quad * 8]);
        f32x4 acc[4];
        for (int nt = 0; nt < 4; nt++) acc[nt] = (f32x4){0.f, 0.f, 0.f, 0.f};
        for (int k = 0; k < 8; k++){
            int d0 = k * 32 + quad * 8;
            for (int nt = 0; nt < 4; nt++){
                int o = w * 64 + nt * 16 + l15;
                v8bf bfr = cvt8(&W1[o * 512 + d0]);
                acc[nt] = mfma16(xa[k], bfr, acc[nt]);
            }
        }
        for (int nt = 0; nt < 4; nt++){
            int o = w * 64 + nt * 16 + l15;
            float bb = b1[o];
            for (int r = 0; r < 4; r++)
                A[(bs0 + quad * 4 + r) * 256 + o] = acc[nt][r] + bb;
        }
    } else {
        int idx8 = (bid - 64) * 256 + tid;   // < 57600
        if (idx8 < 57344){
            const float* srcp;
            u16* dstp;
            if (idx8 < 24576){ srcp = Wih + idx8 * 8;             dstp = wihb + idx8 * 8; }
            else if (idx8 < 49152){ int i = idx8 - 24576; srcp = Whh + i * 8; dstp = whhb + i * 8; }
            else { int i = idx8 - 49152; srcp = W2 + i * 8; dstp = w2b + i * 8; }
            float4 a = *(const float4*)srcp;
            float4 b = *(const float4*)(srcp + 4);
            union { u16 h[8]; uint4 v; } pk;
            pk.h[0] = f2bfu(a.x); pk.h[1] = f2bfu(a.y);
            pk.h[2] = f2bfu(a.z); pk.h[3] = f2bfu(a.w);
            pk.h[4] = f2bfu(b.x); pk.h[5] = f2bfu(b.y);
            pk.h[6] = f2bfu(b.z); pk.h[7] = f2bfu(b.w);
            *(uint4*)dstp = pk.v;
        } else if (idx8 < 57600){
            int o = idx8 - 57344;
            float s = 0.f;
            const float4* p = (const float4*)&W1[o * 512 + 256];
            for (int j = 0; j < 64; j++){
                float4 v = p[j];
                s += v.x + v.y + v.z + v.w;
            }
            wb[o] = s;
        }
    }
}

// =========== k_mid: causal [0,512) | gx [512,896) | metrics [896,1792) ======
__global__ __launch_bounds__(256, 2) void k_mid(
        const float* __restrict__ feat, const u16* __restrict__ wihb,
        const float* __restrict__ bih,  u16* __restrict__ gxb,
        const float* __restrict__ Aws,  const float* __restrict__ wbws,
        const u16* __restrict__ w2b,    const float* __restrict__ tgt,
        const float* __restrict__ b2,   float* __restrict__ part,
        float* __restrict__ out){
    __shared__ __align__(16) unsigned char smem[69632];
    const int tid = threadIdx.x, lane = tid & 63, w = tid >> 6;
    const int l15 = lane & 15, quad = lane >> 4;

    if (blockIdx.x >= 896){
        // ---------------- metrics ----------------
        const int pair = (blockIdx.x - 896) * 4 + (tid >> 6);
        const int l = pair >> 9, s = pair & 511;
        float stab = 0.f, emer = 0.f;
        for (int b = 0; b < 2; b++){
            const float* p = feat + ((size_t)((b * 8 + l) * 512 + s)) * 256;
            const float* n = feat + ((size_t)((b * 8 + l + 1) * 512 + s)) * 256;
            float4 pv = *(const float4*)(p + lane * 4);
            float4 nv = *(const float4*)(n + lane * 4);
            float dot = pv.x * nv.x + pv.y * nv.y + pv.z * nv.z + pv.w * nv.w;
            float na2 = pv.x * pv.x + pv.y * pv.y + pv.z * pv.z + pv.w * pv.w;
            float nb2 = nv.x * nv.x + nv.y * nv.y + nv.z * nv.z + nv.w * nv.w;
            float ap = ((pv.x > 0.1f) ? 1.f : 0.f) + ((pv.y > 0.1f) ? 1.f : 0.f)
                     + ((pv.z > 0.1f) ? 1.f : 0.f) + ((pv.w > 0.1f) ? 1.f : 0.f);
            float an = ((nv.x > 0.1f) ? 1.f : 0.f) + ((nv.y > 0.1f) ? 1.f : 0.f)
                     + ((nv.z > 0.1f) ? 1.f : 0.f) + ((nv.w > 0.1f) ? 1.f : 0.f);
            for (int off = 32; off > 0; off >>= 1){
                dot += __shfl_xor(dot, off);
                na2 += __shfl_xor(na2, off);
                nb2 += __shfl_xor(nb2, off);
                ap  += __shfl_xor(ap,  off);
                an  += __shfl_xor(an,  off);
            }
            float na = fmaxf(__builtin_sqrtf(na2), 1e-8f);
            float nb = fmaxf(__builtin_sqrtf(nb2), 1e-8f);
            stab += dot / (na * nb);
            emer += (an - ap);
        }
        if ((lane & 63) == 0){
            int o = l * 512 + s;
            float e = emer * 0.5f * (1.0f / 256.0f);
            out[OUT_STAB  + o] = stab * 0.5f;
            out[OUT_EMER  + o] = e;
            out[OUT_DECAY + o] = -e;
        }
        return;
    }

    if (blockIdx.x >= 512){
        // ---------------- gx GEMM (bf16 output) ----------------
        const int gid = blockIdx.x - 512;
        const int mb = gid / 6, nb = gid % 6;
        u16* blds = (u16*)smem;   // 128 x 256 u16, swizzled

        {
            int r = tid >> 1, half = tid & 1;
            const uint4* gsrc = (const uint4*)&wihb[(nb * 128 + r) * 256 + half * 128];
            for (int j = 0; j < 16; j++){
                int c = half * 16 + j;
                *(uint4*)&blds[r * 256 + ((c ^ (r & 31)) << 3)] = gsrc[j];
            }
        }

        v8bf af[2][8];
        for (int mt = 0; mt < 2; mt++){
            int r = mb * 128 + w * 32 + mt * 16 + l15;
            int n = r >> 3, t = r & 7;
            int b = n >> 9, s = n & 511;
            const float* xp = feat + ((size_t)((b * 8 + t) * 512 + s)) * 256;
            for (int kk = 0; kk < 8; kk++)
                af[mt][kk] = cvt8(xp + kk * 32 + quad * 8);
        }
        __syncthreads();

        f32x4 acc[2][8];
        for (int mt = 0; mt < 2; mt++) for (int nt = 0; nt < 8; nt++)
            acc[mt][nt] = (f32x4){0.f, 0.f, 0.f, 0.f};
        for (int kk = 0; kk < 8; kk++){
            int kq = kk * 4 + quad;
            for (int nt = 0; nt < 8; nt++){
                int pl = nt * 16 + l15;
                v8bf bf = *(const v8bf*)&blds[pl * 256 + ((kq ^ (pl & 31)) << 3)];
                acc[0][nt] = mfma16(af[0][kk], bf, acc[0][nt]);
                acc[1][nt] = mfma16(af[1][kk], bf, acc[1][nt]);
            }
        }
        for (int nt = 0; nt < 8; nt++){
            int g = nb * 128 + nt * 16 + l15;
            float bias = bih[g];
            for (int mt = 0; mt < 2; mt++)
                for (int rr = 0; rr < 4; rr++){
                    int row = mb * 128 + w * 32 + mt * 16 + quad * 4 + rr;
                    gxb[(size_t)row * 768 + g] = f2bfu(acc[mt][nt][rr] + bias);
                }
        }
        return;
    }

    // ---------------- causal (r12-proven, swizzled) ----------------
    const int bidc = blockIdx.x;
    const int chunk = bidc >> 2, q = bidc & 3;
    const int i0 = (q & 1) * 128, p0 = (q >> 1) * 128;

    u16*  w2s  = (u16*)smem;               // 65536 B, swizzled
    float* a_db = (float*)(smem + 65536);  //  2048 B  [2][256]
    float* t_db = (float*)(smem + 67584);  //  1024 B  [2][128]
    float* wb_s = (float*)(smem + 68608);  //  1024 B

    {
        int r = tid >> 1, half = tid & 1;
        const uint4* gsrc = (const uint4*)&w2b[(p0 + r) * 256 + half * 128];
        for (int j = 0; j < 16; j++){
            int c = half * 16 + j;
            *(uint4*)&w2s[r * 256 + ((c ^ (r & 31)) << 3)] = gsrc[j];
        }
    }
    wb_s[tid] = wbws[tid];
    a_db[tid] = Aws[chunk * 8 * 256 + tid];
    if (tid < 128) t_db[tid] = tgt[(chunk * 8) * 256 + i0 + tid];

    float bb[8];
    for (int nt = 0; nt < 8; nt++) bb[nt] = b2[p0 + nt * 16 + l15];

    f32x4 sig[2][8];
    for (int mt = 0; mt < 2; mt++) for (int nt = 0; nt < 8; nt++)
        sig[mt][nt] = (f32x4){0.f, 0.f, 0.f, 0.f};

    for (int ss = 0; ss < 8; ss++){
        __syncthreads();
        if (ss < 7){
            int nb = (ss + 1) & 1;
            a_db[nb * 256 + tid] = Aws[(chunk * 8 + ss + 1) * 256 + tid];
            if (tid < 128) t_db[nb * 128 + tid] = tgt[(chunk * 8 + ss + 1) * 256 + i0 + tid];
        }
        const int cb = ss & 1;
        float tv0 = t_db[cb * 128 + w * 32 + l15];
        float tv1 = t_db[cb * 128 + w * 32 + 16 + l15];

        f32x4 acc[2][8];
        for (int mt = 0; mt < 2; mt++) for (int nt = 0; nt < 8; nt++)
            acc[mt][nt] = (f32x4){0.f, 0.f, 0.f, 0.f};

        for (int k = 0; k < 8; k++){
            const int o0 = k * 32 + quad * 8;
            const int kq = k * 4 + quad;
            float4 a0  = *(const float4*)&a_db[cb * 256 + o0];
            float4 a1  = *(const float4*)&a_db[cb * 256 + o0 + 4];
            float4 w0  = *(const float4*)&wb_s[o0];
            float4 w1v = *(const float4*)&wb_s[o0 + 4];
            v8bf afr0, afr1;
            {
                float t = tv0;
                afr0[0] = (__bf16)fmaxf(fmaf(t, w0.x,  a0.x), 0.f);
                afr0[1] = (__bf16)fmaxf(fmaf(t, w0.y,  a0.y), 0.f);
                afr0[2] = (__bf16)fmaxf(fmaf(t, w0.z,  a0.z), 0.f);
                afr0[3] = (__bf16)fmaxf(fmaf(t, w0.w,  a0.w), 0.f);
                afr0[4] = (__bf16)fmaxf(fmaf(t, w1v.x, a1.x), 0.f);
                afr0[5] = (__bf16)fmaxf(fmaf(t, w1v.y, a1.y), 0.f);
                afr0[6] = (__bf16)fmaxf(fmaf(t, w1v.z, a1.z), 0.f);
                afr0[7] = (__bf16)fmaxf(fmaf(t, w1v.w, a1.w), 0.f);
            }
            {
                float t = tv1;
                afr1[0] = (__bf16)fmaxf(fmaf(t, w0.x,  a0.x), 0.f);
                afr1[1] = (__bf16)fmaxf(fmaf(t, w0.y,  a0.y), 0.f);
                afr1[2] = (__bf16)fmaxf(fmaf(t, w0.z,  a0.z), 0.f);
                afr1[3] = (__bf16)fmaxf(fmaf(t, w0.w,  a0.w), 0.f);
                afr1[4] = (__bf16)fmaxf(fmaf(t, w1v.x, a1.x), 0.f);
                afr1[5] = (__bf16)fmaxf(fmaf(t, w1v.y, a1.y), 0.f);
                afr1[6] = (__bf16)fmaxf(fmaf(t, w1v.z, a1.z), 0.f);
                afr1[7] = (__bf16)fmaxf(fmaf(t, w1v.w, a1.w), 0.f);
            }
            for (int nt = 0; nt < 8; nt++){
                int pl = nt * 16 + l15;
                v8bf bfr = *(const v8bf*)&w2s[pl * 256 + ((kq ^ (pl & 31)) << 3)];
                acc[0][nt] = mfma16(afr0, bfr, acc[0][nt]);
                acc[1][nt] = mfma16(afr1, bfr, acc[1][nt]);
            }
        }
        for (int mt = 0; mt < 2; mt++)
            for (int nt = 0; nt < 8; nt++)
                for (int r = 0; r < 4; r++)
                    sig[mt][nt][r] += sigmoidf_fast(acc[mt][nt][r] + bb[nt]);
    }

    float* pp = part + (size_t)chunk * 65536;
    for (int mt = 0; mt < 2; mt++)
        for (int r = 0; r < 4; r++){
            int i = i0 + w * 32 + mt * 16 + quad * 4 + r;
            for (int nt = 0; nt < 8; nt++){
                int p = p0 + nt * 16 + l15;
                pp[i * 256 + p] = sig[mt][nt][r];
            }
        }
}

// =========== k_final: gru [0,128) x 8 seqs | creduce [128,256) ==============
__global__ __launch_bounds__(512) void k_final(
        const u16* __restrict__ gxb, const u16* __restrict__ whhb,
        const float* __restrict__ bhh, const float* __restrict__ part,
        float* __restrict__ out){
    if (blockIdx.x >= 128){
        const int idx = (blockIdx.x - 128) * 512 + threadIdx.x;  // 65536
        float s = 0.f;
        for (int c = 0; c < 128; c++)
            s += part[(size_t)c * 65536 + idx];
        out[OUT_CAUSAL + idx] = s * (1.0f / 1024.0f);
        return;
    }
    // ---- gru: 8 sequences per block (M=8 in the 16-row MFMA tile) ----
    const int n0 = blockIdx.x * 8;
    const int tid = threadIdx.x, lane = tid & 63, wv = tid >> 6;
    const int l15 = lane & 15, quad = lane >> 4;
    const int g0 = wv * 96;

    __shared__ float h_lds[16 * 260];
    __shared__ float g_lds[16 * 776];

    v8bf wreg[3][8];
    for (int nt = 0; nt < 3; nt++)
        for (int k = 0; k < 8; k++)
            wreg[nt][k] = *(const v8bf*)&whhb[(g0 + nt * 16 + l15) * 256 + k * 32 + quad * 8];

    float bias[6];
    for (int nt = 0; nt < 6; nt++) bias[nt] = bhh[g0 + nt * 16 + l15];

    for (int e = tid; e < 16 * 260; e += 512) h_lds[e] = 0.f;

    const int seq = tid >> 5, d0 = (tid & 31) * 8;   // valid work: tid < 256
    __syncthreads();

    for (int t = 0; t < 8; t++){
        v8bf ha[8];
        for (int k = 0; k < 8; k++)
            ha[k] = cvt8(&h_lds[l15 * 260 + k * 32 + quad * 8]);
        f32x4 acc[6];
        for (int nt = 0; nt < 6; nt++) acc[nt] = (f32x4){0.f, 0.f, 0.f, 0.f};
        for (int k = 0; k < 8; k++){
            int dk = k * 32 + quad * 8;
            acc[0] = mfma16(ha[k], wreg[0][k], acc[0]);
            acc[1] = mfma16(ha[k], wreg[1][k], acc[1]);
            acc[2] = mfma16(ha[k], wreg[2][k], acc[2]);
            for (int nt = 3; nt < 6; nt++){
                v8bf bf = *(const v8bf*)&whhb[(g0 + nt * 16 + l15) * 256 + dk];
                acc[nt] = mfma16(ha[k], bf, acc[nt]);
            }
        }
        for (int nt = 0; nt < 6; nt++){
            int g = g0 + nt * 16 + l15;
            for (int rr = 0; rr < 4; rr++)
                g_lds[(quad * 4 + rr) * 776 + g] = acc[nt][rr] + bias[nt];
        }
        // prefetch bf16 gx (only the 256 updater threads)
        uint4 xr, xz, xn;
        if (tid < 256){
            const u16* gxp = gxb + ((size_t)(n0 + seq) * 8 + t) * 768 + d0;
            xr = *(const uint4*)(gxp);
            xz = *(const uint4*)(gxp + 256);
            xn = *(const uint4*)(gxp + 512);
        }
        __syncthreads();
        if (tid < 256){
            const float* gh = &g_lds[seq * 776];
            float* hp = &h_lds[seq * 260 + d0];
            float4 g0a = *(const float4*)&gh[d0];
            float4 g0b = *(const float4*)&gh[d0 + 4];
            float4 g1a = *(const float4*)&gh[256 + d0];
            float4 g1b = *(const float4*)&gh[260 + d0];
            float4 g2a = *(const float4*)&gh[512 + d0];
            float4 g2b = *(const float4*)&gh[516 + d0];
            float4 h0 = *(const float4*)hp;
            float4 h1 = *(const float4*)(hp + 4);
            float gxr[8] = {lo2f(xr.x), hi2f(xr.x), lo2f(xr.y), hi2f(xr.y),
                            lo2f(xr.z), hi2f(xr.z), lo2f(xr.w), hi2f(xr.w)};
            float gxz[8] = {lo2f(xz.x), hi2f(xz.x), lo2f(xz.y), hi2f(xz.y),
                            lo2f(xz.z), hi2f(xz.z), lo2f(xz.w), hi2f(xz.w)};
            float gxn[8] = {lo2f(xn.x), hi2f(xn.x), lo2f(xn.y), hi2f(xn.y),
                            lo2f(xn.z), hi2f(xn.z), lo2f(xn.w), hi2f(xn.w)};
            float ghr[8] = {g0a.x, g0a.y, g0a.z, g0a.w, g0b.x, g0b.y, g0b.z, g0b.w};
            float ghz[8] = {g1a.x, g1a.y, g1a.z, g1a.w, g1b.x, g1b.y, g1b.z, g1b.w};
            float ghn[8] = {g2a.x, g2a.y, g2a.z, g2a.w, g2b.x, g2b.y, g2b.z, g2b.w};
            float hold[8] = {h0.x, h0.y, h0.z, h0.w, h1.x, h1.y, h1.z, h1.w};
            float hn[8];
            #pragma unroll
            for (int j = 0; j < 8; j++){
                float r  = sigmoidf_fast(gxr[j] + ghr[j]);
                float z  = sigmoidf_fast(gxz[j] + ghz[j]);
                float nn = tanhf_fast(fmaf(r, ghn[j], gxn[j]));
                hn[j] = (1.f - z) * nn + z * hold[j];
            }
            float4 v0 = {hn[0], hn[1], hn[2], hn[3]};
            float4 v1 = {hn[4], hn[5], hn[6], hn[7]};
            *(float4*)hp       = v0;
            *(float4*)(hp + 4) = v1;
            float* ep = out + OUT_EVO + ((size_t)(n0 + seq) * 8 + t) * 256 + d0;
            *(float4*)ep       = v0;
            *(float4*)(ep + 4) = v1;
        }
        __syncthreads();
    }
}

extern "C" void kernel_launch(void* const* d_in, const int* in_sizes, int n_in,
                              void* d_out, int out_size, void* d_ws, size_t ws_size,
                              hipStream_t stream){
    const float* feat = (const float*)d_in[0];
    const float* src  = (const float*)d_in[1];
    const float* tgt  = (const float*)d_in[2];
    const float* Wih  = (const float*)d_in[3];
    const float* Whh  = (const float*)d_in[4];
    const float* bih  = (const float*)d_in[5];
    const float* bhh  = (const float*)d_in[6];
    const float* W1   = (const float*)d_in[7];
    const float* b1   = (const float*)d_in[8];
    const float* W2   = (const float*)d_in[9];
    const float* b2   = (const float*)d_in[10];
    float* out = (float*)d_out;
    char* ws = (char*)d_ws;

    float* wb   = (float*)(ws + WS_WB);
    u16*   wihb = (u16*)(ws + WS_WIHB);
    u16*   whhb = (u16*)(ws + WS_WHHB);
    u16*   w2b  = (u16*)(ws + WS_W2B);
    float* Aws  = (float*)(ws + WS_A);
    u16*   gxb  = (u16*)(ws + WS_GX);
    float* part = (float*)(ws + WS_PART);

    k_pre  <<<289,  256, 0, stream>>>(src, Wih, Whh, W1, b1, W2,
                                      wihb, whhb, w2b, wb, Aws);
    k_mid  <<<1792, 256, 0, stream>>>(feat, wihb, bih, gxb,
                                      Aws, wb, w2b, tgt, b2, part, out);
    k_final<<<256,  512, 0, stream>>>(gxb, whhb, bhh, part, out);
}

// Round 14
// 211.495 us; speedup vs baseline: 1.1758x; 1.0128x over previous
//
#include <hip/hip_runtime.h>
#include <hip/hip_bf16.h>
#include <stdint.h>

typedef unsigned short u16;
typedef __bf16 v8bf __attribute__((ext_vector_type(8)));
typedef __bf16 v2bf __attribute__((ext_vector_type(2)));
typedef float f32x4 __attribute__((ext_vector_type(4)));
typedef float v2f  __attribute__((ext_vector_type(2)));

// ws byte offsets (total 60,817,408 B — proven footprint)
#define WS_WB    0u
#define WS_WIHB  4096u
#define WS_WHHB  397312u
#define WS_W2B   790528u
#define WS_A     921600u
#define WS_GX    2097152u     // u16[8192*768] (bf16)
#define WS_PART  27262976u

// out (fp32) element offsets
#define OUT_STAB   0
#define OUT_EMER   3584
#define OUT_DECAY  7168
#define OUT_CAUSAL 10752
#define OUT_EVO    76288

__device__ __forceinline__ u16 f2bfu(float f){
    union { float f; uint32_t u; } v; v.f = f;
    uint32_t u = v.u;
    return (u16)((u + 0x7fffu + ((u >> 16) & 1u)) >> 16);
}
__device__ __forceinline__ float hi2f(uint32_t w){
    union { uint32_t u; float f; } v; v.u = w & 0xFFFF0000u; return v.f;
}
__device__ __forceinline__ float lo2f(uint32_t w){
    union { uint32_t u; float f; } v; v.u = w << 16; return v.f;
}
__device__ __forceinline__ float sigmoidf_fast(float x){
    float e = __builtin_amdgcn_exp2f(-1.4426950408889634f * x);
    return __builtin_amdgcn_rcpf(1.0f + e);
}
__device__ __forceinline__ float tanhf_fast(float x){
    float e = __builtin_amdgcn_exp2f(-2.8853900817779268f * x);
    return __builtin_amdgcn_rcpf(1.0f + e) * 2.0f - 1.0f;
}
__device__ __forceinline__ f32x4 mfma16(v8bf a, v8bf b, f32x4 c){
    return __builtin_amdgcn_mfma_f32_16x16x32_bf16(a, b, c, 0, 0, 0);
}
__device__ __forceinline__ v8bf cvt8(const float* p){
    float4 a = *(const float4*)p;
    float4 b = *(const float4*)(p + 4);
    v8bf r;
    r[0] = (__bf16)a.x; r[1] = (__bf16)a.y; r[2] = (__bf16)a.z; r[3] = (__bf16)a.w;
    r[4] = (__bf16)b.x; r[5] = (__bf16)b.y; r[6] = (__bf16)b.z; r[7] = (__bf16)b.w;
    return r;
}

// =========== k_pre: Agemm [0,64) | prep-vec8 [64,289) =======================
__global__ __launch_bounds__(256) void k_pre(
        const float* __restrict__ src,
        const float* __restrict__ Wih,  const float* __restrict__ Whh,
        const float* __restrict__ W1,   const float* __restrict__ b1,
        const float* __restrict__ W2,
        u16* __restrict__ wihb, u16* __restrict__ whhb, u16* __restrict__ w2b,
        float* __restrict__ wb, float* __restrict__ A){
    const int bid = blockIdx.x, tid = threadIdx.x;
    if (bid < 64){
        const int bs0 = bid * 16;
        const int lane = tid & 63, w = tid >> 6;
        const int l15 = lane & 15, quad = lane >> 4;
        v8bf xa[8];
        for (int k = 0; k < 8; k++)
            xa[k] = cvt8(&src[(bs0 + l15) * 256 + k * 32 + quad * 8]);
        f32x4 acc[4];
        for (int nt = 0; nt < 4; nt++) acc[nt] = (f32x4){0.f, 0.f, 0.f, 0.f};
        for (int k = 0; k < 8; k++){
            int d0 = k * 32 + quad * 8;
            for (int nt = 0; nt < 4; nt++){
                int o = w * 64 + nt * 16 + l15;
                v8bf bfr = cvt8(&W1[o * 512 + d0]);
                acc[nt] = mfma16(xa[k], bfr, acc[nt]);
            }
        }
        for (int nt = 0; nt < 4; nt++){
            int o = w * 64 + nt * 16 + l15;
            float bb = b1[o];
            for (int r = 0; r < 4; r++)
                A[(bs0 + quad * 4 + r) * 256 + o] = acc[nt][r] + bb;
        }
    } else {
        int idx8 = (bid - 64) * 256 + tid;   // < 57600
        if (idx8 < 57344){
            const float* srcp;
            u16* dstp;
            if (idx8 < 24576){ srcp = Wih + idx8 * 8;             dstp = wihb + idx8 * 8; }
            else if (idx8 < 49152){ int i = idx8 - 24576; srcp = Whh + i * 8; dstp = whhb + i * 8; }
            else { int i = idx8 - 49152; srcp = W2 + i * 8; dstp = w2b + i * 8; }
            float4 a = *(const float4*)srcp;
            float4 b = *(const float4*)(srcp + 4);
            union { u16 h[8]; uint4 v; } pk;
            pk.h[0] = f2bfu(a.x); pk.h[1] = f2bfu(a.y);
            pk.h[2] = f2bfu(a.z); pk.h[3] = f2bfu(a.w);
            pk.h[4] = f2bfu(b.x); pk.h[5] = f2bfu(b.y);
            pk.h[6] = f2bfu(b.z); pk.h[7] = f2bfu(b.w);
            *(uint4*)dstp = pk.v;
        } else if (idx8 < 57600){
            int o = idx8 - 57344;
            float s = 0.f;
            const float4* p = (const float4*)&W1[o * 512 + 256];
            for (int j = 0; j < 64; j++){
                float4 v = p[j];
                s += v.x + v.y + v.z + v.w;
            }
            wb[o] = s;
        }
    }
}

// =========== k_mid: causal [0,512) | gx [512,896) | metrics [896,1792) ======
__global__ __launch_bounds__(256, 2) void k_mid(
        const float* __restrict__ feat, const u16* __restrict__ wihb,
        const float* __restrict__ bih,  u16* __restrict__ gxb,
        const float* __restrict__ Aws,  const float* __restrict__ wbws,
        const u16* __restrict__ w2b,    const float* __restrict__ tgt,
        const float* __restrict__ b2,   float* __restrict__ part,
        float* __restrict__ out){
    __shared__ __align__(16) unsigned char smem[69632];
    const int tid = threadIdx.x, lane = tid & 63, w = tid >> 6;
    const int l15 = lane & 15, quad = lane >> 4;

    if (blockIdx.x >= 896){
        // ---------------- metrics ----------------
        const int pair = (blockIdx.x - 896) * 4 + (tid >> 6);
        const int l = pair >> 9, s = pair & 511;
        float stab = 0.f, emer = 0.f;
        for (int b = 0; b < 2; b++){
            const float* p = feat + ((size_t)((b * 8 + l) * 512 + s)) * 256;
            const float* n = feat + ((size_t)((b * 8 + l + 1) * 512 + s)) * 256;
            float4 pv = *(const float4*)(p + lane * 4);
            float4 nv = *(const float4*)(n + lane * 4);
            float dot = pv.x * nv.x + pv.y * nv.y + pv.z * nv.z + pv.w * nv.w;
            float na2 = pv.x * pv.x + pv.y * pv.y + pv.z * pv.z + pv.w * pv.w;
            float nb2 = nv.x * nv.x + nv.y * nv.y + nv.z * nv.z + nv.w * nv.w;
            float ap = ((pv.x > 0.1f) ? 1.f : 0.f) + ((pv.y > 0.1f) ? 1.f : 0.f)
                     + ((pv.z > 0.1f) ? 1.f : 0.f) + ((pv.w > 0.1f) ? 1.f : 0.f);
            float an = ((nv.x > 0.1f) ? 1.f : 0.f) + ((nv.y > 0.1f) ? 1.f : 0.f)
                     + ((nv.z > 0.1f) ? 1.f : 0.f) + ((nv.w > 0.1f) ? 1.f : 0.f);
            for (int off = 32; off > 0; off >>= 1){
                dot += __shfl_xor(dot, off);
                na2 += __shfl_xor(na2, off);
                nb2 += __shfl_xor(nb2, off);
                ap  += __shfl_xor(ap,  off);
                an  += __shfl_xor(an,  off);
            }
            float na = fmaxf(__builtin_sqrtf(na2), 1e-8f);
            float nb = fmaxf(__builtin_sqrtf(nb2), 1e-8f);
            stab += dot / (na * nb);
            emer += (an - ap);
        }
        if ((lane & 63) == 0){
            int o = l * 512 + s;
            float e = emer * 0.5f * (1.0f / 256.0f);
            out[OUT_STAB  + o] = stab * 0.5f;
            out[OUT_EMER  + o] = e;
            out[OUT_DECAY + o] = -e;
        }
        return;
    }

    if (blockIdx.x >= 512){
        // ---------------- gx GEMM (bf16 output) ----------------
        const int gid = blockIdx.x - 512;
        const int mb = gid / 6, nb = gid % 6;
        u16* blds = (u16*)smem;   // 128 x 256 u16, swizzled

        {
            int r = tid >> 1, half = tid & 1;
            const uint4* gsrc = (const uint4*)&wihb[(nb * 128 + r) * 256 + half * 128];
            for (int j = 0; j < 16; j++){
                int c = half * 16 + j;
                *(uint4*)&blds[r * 256 + ((c ^ (r & 31)) << 3)] = gsrc[j];
            }
        }

        v8bf af[2][8];
        for (int mt = 0; mt < 2; mt++){
            int r = mb * 128 + w * 32 + mt * 16 + l15;
            int n = r >> 3, t = r & 7;
            int b = n >> 9, s = n & 511;
            const float* xp = feat + ((size_t)((b * 8 + t) * 512 + s)) * 256;
            for (int kk = 0; kk < 8; kk++)
                af[mt][kk] = cvt8(xp + kk * 32 + quad * 8);
        }
        __syncthreads();

        f32x4 acc[2][8];
        for (int mt = 0; mt < 2; mt++) for (int nt = 0; nt < 8; nt++)
            acc[mt][nt] = (f32x4){0.f, 0.f, 0.f, 0.f};
        for (int kk = 0; kk < 8; kk++){
            int kq = kk * 4 + quad;
            for (int nt = 0; nt < 8; nt++){
                int pl = nt * 16 + l15;
                v8bf bf = *(const v8bf*)&blds[pl * 256 + ((kq ^ (pl & 31)) << 3)];
                acc[0][nt] = mfma16(af[0][kk], bf, acc[0][nt]);
                acc[1][nt] = mfma16(af[1][kk], bf, acc[1][nt]);
            }
        }
        for (int nt = 0; nt < 8; nt++){
            int g = nb * 128 + nt * 16 + l15;
            float bias = bih[g];
            for (int mt = 0; mt < 2; mt++)
                for (int rr = 0; rr < 4; rr++){
                    int row = mb * 128 + w * 32 + mt * 16 + quad * 4 + rr;
                    gxb[(size_t)row * 768 + g] = f2bfu(acc[mt][nt][rr] + bias);
                }
        }
        return;
    }

    // ---------------- causal (packed-f32 h-construct) ----------------
    const int bidc = blockIdx.x;
    const int chunk = bidc >> 2, q = bidc & 3;
    const int i0 = (q & 1) * 128, p0 = (q >> 1) * 128;

    u16*  w2s  = (u16*)smem;               // 65536 B, swizzled
    float* a_db = (float*)(smem + 65536);  //  2048 B  [2][256]
    float* t_db = (float*)(smem + 67584);  //  1024 B  [2][128]
    float* wb_s = (float*)(smem + 68608);  //  1024 B

    {
        int r = tid >> 1, half = tid & 1;
        const uint4* gsrc = (const uint4*)&w2b[(p0 + r) * 256 + half * 128];
        for (int j = 0; j < 16; j++){
            int c = half * 16 + j;
            *(uint4*)&w2s[r * 256 + ((c ^ (r & 31)) << 3)] = gsrc[j];
        }
    }
    wb_s[tid] = wbws[tid];
    a_db[tid] = Aws[chunk * 8 * 256 + tid];
    if (tid < 128) t_db[tid] = tgt[(chunk * 8) * 256 + i0 + tid];

    float bb[8];
    for (int nt = 0; nt < 8; nt++) bb[nt] = b2[p0 + nt * 16 + l15];

    f32x4 sig[2][8];
    for (int mt = 0; mt < 2; mt++) for (int nt = 0; nt < 8; nt++)
        sig[mt][nt] = (f32x4){0.f, 0.f, 0.f, 0.f};

    const v2f z2 = {0.f, 0.f};

    for (int ss = 0; ss < 8; ss++){
        __syncthreads();
        if (ss < 7){
            int nb = (ss + 1) & 1;
            a_db[nb * 256 + tid] = Aws[(chunk * 8 + ss + 1) * 256 + tid];
            if (tid < 128) t_db[nb * 128 + tid] = tgt[(chunk * 8 + ss + 1) * 256 + i0 + tid];
        }
        const int cb = ss & 1;
        v2f tv0 = {t_db[cb * 128 + w * 32 + l15],      t_db[cb * 128 + w * 32 + l15]};
        v2f tv1 = {t_db[cb * 128 + w * 32 + 16 + l15], t_db[cb * 128 + w * 32 + 16 + l15]};

        f32x4 acc[2][8];
        for (int mt = 0; mt < 2; mt++) for (int nt = 0; nt < 8; nt++)
            acc[mt][nt] = (f32x4){0.f, 0.f, 0.f, 0.f};

        for (int k = 0; k < 8; k++){
            const int o0 = k * 32 + quad * 8;
            const int kq = k * 4 + quad;
            const v2f* a2 = (const v2f*)&a_db[cb * 256 + o0];   // 4 pairs
            const v2f* w2 = (const v2f*)&wb_s[o0];
            union { v2bf b[4]; v8bf v; } u0, u1;
            #pragma unroll
            for (int j = 0; j < 4; j++){
                v2f h0 = __builtin_elementwise_max(a2[j] + tv0 * w2[j], z2);  // v_pk_fma + v_pk_max
                v2f h1 = __builtin_elementwise_max(a2[j] + tv1 * w2[j], z2);
                u0.b[j] = __builtin_convertvector(h0, v2bf);
                u1.b[j] = __builtin_convertvector(h1, v2bf);
            }
            v8bf afr0 = u0.v, afr1 = u1.v;
            for (int nt = 0; nt < 8; nt++){
                int pl = nt * 16 + l15;
                v8bf bfr = *(const v8bf*)&w2s[pl * 256 + ((kq ^ (pl & 31)) << 3)];
                acc[0][nt] = mfma16(afr0, bfr, acc[0][nt]);
                acc[1][nt] = mfma16(afr1, bfr, acc[1][nt]);
            }
        }
        for (int mt = 0; mt < 2; mt++)
            for (int nt = 0; nt < 8; nt++)
                for (int r = 0; r < 4; r++)
                    sig[mt][nt][r] += sigmoidf_fast(acc[mt][nt][r] + bb[nt]);
    }

    float* pp = part + (size_t)chunk * 65536;
    for (int mt = 0; mt < 2; mt++)
        for (int r = 0; r < 4; r++){
            int i = i0 + w * 32 + mt * 16 + quad * 4 + r;
            for (int nt = 0; nt < 8; nt++){
                int p = p0 + nt * 16 + l15;
                pp[i * 256 + p] = sig[mt][nt][r];
            }
        }
}

// =========== k_final: gru [0,128) x 8 seqs | creduce [128,256) ==============
__global__ __launch_bounds__(512) void k_final(
        const u16* __restrict__ gxb, const u16* __restrict__ whhb,
        const float* __restrict__ bhh, const float* __restrict__ part,
        float* __restrict__ out){
    if (blockIdx.x >= 128){
        const int idx = (blockIdx.x - 128) * 512 + threadIdx.x;  // 65536
        float s = 0.f;
        for (int c = 0; c < 128; c++)
            s += part[(size_t)c * 65536 + idx];
        out[OUT_CAUSAL + idx] = s * (1.0f / 1024.0f);
        return;
    }
    const int n0 = blockIdx.x * 8;
    const int tid = threadIdx.x, lane = tid & 63, wv = tid >> 6;
    const int l15 = lane & 15, quad = lane >> 4;
    const int g0 = wv * 96;

    __shared__ float h_lds[16 * 260];
    __shared__ float g_lds[16 * 776];

    v8bf wreg[3][8];
    for (int nt = 0; nt < 3; nt++)
        for (int k = 0; k < 8; k++)
            wreg[nt][k] = *(const v8bf*)&whhb[(g0 + nt * 16 + l15) * 256 + k * 32 + quad * 8];

    float bias[6];
    for (int nt = 0; nt < 6; nt++) bias[nt] = bhh[g0 + nt * 16 + l15];

    for (int e = tid; e < 16 * 260; e += 512) h_lds[e] = 0.f;

    const int seq = tid >> 5, d0 = (tid & 31) * 8;   // valid work: tid < 256
    __syncthreads();

    for (int t = 0; t < 8; t++){
        v8bf ha[8];
        for (int k = 0; k < 8; k++)
            ha[k] = cvt8(&h_lds[l15 * 260 + k * 32 + quad * 8]);
        f32x4 acc[6];
        for (int nt = 0; nt < 6; nt++) acc[nt] = (f32x4){0.f, 0.f, 0.f, 0.f};
        for (int k = 0; k < 8; k++){
            int dk = k * 32 + quad * 8;
            acc[0] = mfma16(ha[k], wreg[0][k], acc[0]);
            acc[1] = mfma16(ha[k], wreg[1][k], acc[1]);
            acc[2] = mfma16(ha[k], wreg[2][k], acc[2]);
            for (int nt = 3; nt < 6; nt++){
                v8bf bf = *(const v8bf*)&whhb[(g0 + nt * 16 + l15) * 256 + dk];
                acc[nt] = mfma16(ha[k], bf, acc[nt]);
            }
        }
        for (int nt = 0; nt < 6; nt++){
            int g = g0 + nt * 16 + l15;
            for (int rr = 0; rr < 4; rr++)
                g_lds[(quad * 4 + rr) * 776 + g] = acc[nt][rr] + bias[nt];
        }
        uint4 xr, xz, xn;
        if (tid < 256){
            const u16* gxp = gxb + ((size_t)(n0 + seq) * 8 + t) * 768 + d0;
            xr = *(const uint4*)(gxp);
            xz = *(const uint4*)(gxp + 256);
            xn = *(const uint4*)(gxp + 512);
        }
        __syncthreads();
        if (tid < 256){
            const float* gh = &g_lds[seq * 776];
            float* hp = &h_lds[seq * 260 + d0];
            float4 g0a = *(const float4*)&gh[d0];
            float4 g0b = *(const float4*)&gh[d0 + 4];
            float4 g1a = *(const float4*)&gh[256 + d0];
            float4 g1b = *(const float4*)&gh[260 + d0];
            float4 g2a = *(const float4*)&gh[512 + d0];
            float4 g2b = *(const float4*)&gh[516 + d0];
            float4 h0 = *(const float4*)hp;
            float4 h1 = *(const float4*)(hp + 4);
            float gxr[8] = {lo2f(xr.x), hi2f(xr.x), lo2f(xr.y), hi2f(xr.y),
                            lo2f(xr.z), hi2f(xr.z), lo2f(xr.w), hi2f(xr.w)};
            float gxz[8] = {lo2f(xz.x), hi2f(xz.x), lo2f(xz.y), hi2f(xz.y),
                            lo2f(xz.z), hi2f(xz.z), lo2f(xz.w), hi2f(xz.w)};
            float gxn[8] = {lo2f(xn.x), hi2f(xn.x), lo2f(xn.y), hi2f(xn.y),
                            lo2f(xn.z), hi2f(xn.z), lo2f(xn.w), hi2f(xn.w)};
            float ghr[8] = {g0a.x, g0a.y, g0a.z, g0a.w, g0b.x, g0b.y, g0b.z, g0b.w};
            float ghz[8] = {g1a.x, g1a.y, g1a.z, g1a.w, g1b.x, g1b.y, g1b.z, g1b.w};
            float ghn[8] = {g2a.x, g2a.y, g2a.z, g2a.w, g2b.x, g2b.y, g2b.z, g2b.w};
            float hold[8] = {h0.x, h0.y, h0.z, h0.w, h1.x, h1.y, h1.z, h1.w};
            float hn[8];
            #pragma unroll
            for (int j = 0; j < 8; j++){
                float r  = sigmoidf_fast(gxr[j] + ghr[j]);
                float z  = sigmoidf_fast(gxz[j] + ghz[j]);
                float nn = tanhf_fast(fmaf(r, ghn[j], gxn[j]));
                hn[j] = (1.f - z) * nn + z * hold[j];
            }
            float4 v0 = {hn[0], hn[1], hn[2], hn[3]};
            float4 v1 = {hn[4], hn[5], hn[6], hn[7]};
            *(float4*)hp       = v0;
            *(float4*)(hp + 4) = v1;
            float* ep = out + OUT_EVO + ((size_t)(n0 + seq) * 8 + t) * 256 + d0;
            *(float4*)ep       = v0;
            *(float4*)(ep + 4) = v1;
        }
        __syncthreads();
    }
}

extern "C" void kernel_launch(void* const* d_in, const int* in_sizes, int n_in,
                              void* d_out, int out_size, void* d_ws, size_t ws_size,
                              hipStream_t stream){
    const float* feat = (const float*)d_in[0];
    const float* src  = (const float*)d_in[1];
    const float* tgt  = (const float*)d_in[2];
    const float* Wih  = (const float*)d_in[3];
    const float* Whh  = (const float*)d_in[4];
    const float* bih  = (const float*)d_in[5];
    const float* bhh  = (const float*)d_in[6];
    const float* W1   = (const float*)d_in[7];
    const float* b1   = (const float*)d_in[8];
    const float* W2   = (const float*)d_in[9];
    const float* b2   = (const float*)d_in[10];
    float* out = (float*)d_out;
    char* ws = (char*)d_ws;

    float* wb   = (float*)(ws + WS_WB);
    u16*   wihb = (u16*)(ws + WS_WIHB);
    u16*   whhb = (u16*)(ws + WS_WHHB);
    u16*   w2b  = (u16*)(ws + WS_W2B);
    float* Aws  = (float*)(ws + WS_A);
    u16*   gxb  = (u16*)(ws + WS_GX);
    float* part = (float*)(ws + WS_PART);

    k_pre  <<<289,  256, 0, stream>>>(src, Wih, Whh, W1, b1, W2,
                                      wihb, whhb, w2b, wb, Aws);
    k_mid  <<<1792, 256, 0, stream>>>(feat, wihb, bih, gxb,
                                      Aws, wb, w2b, tgt, b2, part, out);
    k_final<<<256,  512, 0, stream>>>(gxb, whhb, bhh, part, out);
}